// Round 2
// baseline (325.710 us; speedup 1.0000x reference)
//
#include <hip/hip_runtime.h>
#include <math.h>

#define HWSZ 65536
#define SDIM 2048
#define NCHUNK 8
#define CHUNKSZ 256
#define INV_TAU 14.285714285714286f
#define EPSN 1e-7f

// ---------------- Kernel A: gather-diff -> MLP -> L2 normalize ----------------
// One wave (64 lanes) per row. Rows: [which(2)][b(8)][s(2048)] = 32768.
__global__ __launch_bounds__(256) void feat_kernel(
    const float* __restrict__ f_q, const float* __restrict__ f_k,
    const float* __restrict__ W0, const float* __restrict__ b0,
    const float* __restrict__ W1, const float* __restrict__ b1,
    const int* __restrict__ c_ids, const int* __restrict__ n_ids,
    float* __restrict__ Fq, float* __restrict__ Fk)
{
    __shared__ float sd[4][64];
    __shared__ float sh[4][64];
    const int w    = threadIdx.x >> 6;
    const int lane = threadIdx.x & 63;
    const int row  = blockIdx.x * 4 + w;      // 0..32767
    const int which = row >> 14;              // 0 = f_q, 1 = f_k
    const int r = row & 16383;
    const int b = r >> 11;
    const int s = r & 2047;

    const float* feat = which ? f_k : f_q;
    const int cid = c_ids[s];
    const int nid = n_ids[s];
    // lane = channel c; feat[b, c, pixel] at (b*64+c)*HW + pixel
    const float* base = feat + ((size_t)(b * 64 + lane)) * HWSZ;
    float d = base[cid] - base[nid];
    sd[w][lane] = d;
    __syncthreads();

    // h[j] = relu(b0[j] + sum_c d[c] * W0[c,j]); lane = j
    float acc = b0[lane];
    #pragma unroll 16
    for (int c = 0; c < 64; ++c)
        acc = fmaf(sd[w][c], W0[c * 64 + lane], acc);
    sh[w][lane] = fmaxf(acc, 0.0f);
    __syncthreads();

    // o[i] = b1[i] + sum_j h[j] * W1[j,i]; lanes 0..15, i = lane
    if (lane < 16) {
        float o = b1[lane];
        #pragma unroll 16
        for (int j = 0; j < 64; ++j)
            o = fmaf(sh[w][j], W1[j * 16 + lane], o);
        float s2 = o * o;
        s2 += __shfl_xor(s2, 1, 16);
        s2 += __shfl_xor(s2, 2, 16);
        s2 += __shfl_xor(s2, 4, 16);
        s2 += __shfl_xor(s2, 8, 16);
        float val = o / (sqrtf(s2) + EPSN);
        float* F = which ? Fk : Fq;
        F[((size_t)(b * SDIM + s)) * 16 + lane] = val;
    }
}

// ---------------- Kernel B: Gram row partial logsumexp sums ----------------
// grid = (S/256, NCHUNK, B); thread -> one s; loops t over its chunk.
// fk row address is wave-uniform per t -> L1/L2-hot (128 KB per b).
__global__ __launch_bounds__(256) void gram_kernel(
    const float* __restrict__ Fq, const float* __restrict__ Fk,
    float* __restrict__ partial, float* __restrict__ diag)
{
    const int s     = blockIdx.x * 256 + threadIdx.x;
    const int chunk = blockIdx.y;
    const int b     = blockIdx.z;

    const float4* q4 = (const float4*)(Fq + ((size_t)(b * SDIM + s)) * 16);
    const float4 qa = q4[0], qb = q4[1], qc = q4[2], qd = q4[3];
    const float* fk = Fk + (size_t)b * SDIM * 16;

    float sum_e = 0.0f;
    float dsave = 0.0f;
    const int t0 = chunk * CHUNKSZ;
    for (int t = t0; t < t0 + CHUNKSZ; ++t) {
        const float4* k4 = (const float4*)(fk + (size_t)t * 16);
        const float4 ka = k4[0], kb = k4[1], kc = k4[2], kd = k4[3];
        float dot = qa.x * ka.x;
        dot = fmaf(qa.y, ka.y, dot); dot = fmaf(qa.z, ka.z, dot); dot = fmaf(qa.w, ka.w, dot);
        dot = fmaf(qb.x, kb.x, dot); dot = fmaf(qb.y, kb.y, dot); dot = fmaf(qb.z, kb.z, dot); dot = fmaf(qb.w, kb.w, dot);
        dot = fmaf(qc.x, kc.x, dot); dot = fmaf(qc.y, kc.y, dot); dot = fmaf(qc.z, kc.z, dot); dot = fmaf(qc.w, kc.w, dot);
        dot = fmaf(qd.x, kd.x, dot); dot = fmaf(qd.y, kd.y, dot); dot = fmaf(qd.z, kd.z, dot); dot = fmaf(qd.w, kd.w, dot);
        sum_e += __expf(fmaf(dot, INV_TAU, -INV_TAU));   // exp(dot/tau - M), M = 1/tau
        if (t == s) dsave = dot;
    }
    partial[((size_t)(b * SDIM + s)) * NCHUNK + chunk] = sum_e;
    if (chunk == (s >> 8)) diag[b * SDIM + s] = dsave;
}

// ---------------- Kernel C: finalize loss ----------------
__global__ __launch_bounds__(256) void loss_kernel(
    const float* __restrict__ partial, const float* __restrict__ diag,
    float* __restrict__ out)
{
    const int idx = blockIdx.x * 256 + threadIdx.x;  // 0..16383 = b*S+s
    float tot = 0.0f;
    #pragma unroll
    for (int c = 0; c < NCHUNK; ++c) tot += partial[(size_t)idx * NCHUNK + c];
    float loss = INV_TAU + logf(tot) - diag[idx] * INV_TAU;

    loss += __shfl_xor(loss, 32, 64);
    loss += __shfl_xor(loss, 16, 64);
    loss += __shfl_xor(loss, 8, 64);
    loss += __shfl_xor(loss, 4, 64);
    loss += __shfl_xor(loss, 2, 64);
    loss += __shfl_xor(loss, 1, 64);

    __shared__ float wsum[4];
    const int lane = threadIdx.x & 63, w = threadIdx.x >> 6;
    if (lane == 0) wsum[w] = loss;
    __syncthreads();
    if (threadIdx.x == 0) {
        float blk = wsum[0] + wsum[1] + wsum[2] + wsum[3];
        atomicAdd(out, blk * (1.0f / 16384.0f));
    }
}

extern "C" void kernel_launch(void* const* d_in, const int* in_sizes, int n_in,
                              void* d_out, int out_size, void* d_ws, size_t ws_size,
                              hipStream_t stream) {
    const float* f_q   = (const float*)d_in[0];
    const float* f_k   = (const float*)d_in[1];
    const float* W0    = (const float*)d_in[2];
    const float* b0    = (const float*)d_in[3];
    const float* W1    = (const float*)d_in[4];
    const float* b1    = (const float*)d_in[5];
    const int*   c_ids = (const int*)d_in[6];
    const int*   n_ids = (const int*)d_in[7];

    float* ws      = (float*)d_ws;
    float* Fq      = ws;                  // B*S*16 = 262144 floats
    float* Fk      = Fq + 262144;         // 262144 floats
    float* partial = Fk + 262144;         // B*S*NCHUNK = 131072 floats
    float* diag    = partial + 131072;    // B*S = 16384 floats
    float* out     = (float*)d_out;

    hipMemsetAsync(d_out, 0, sizeof(float), stream);
    feat_kernel<<<8192, 256, 0, stream>>>(f_q, f_k, W0, b0, W1, b1, c_ids, n_ids, Fq, Fk);
    gram_kernel<<<dim3(SDIM / 256, NCHUNK, 8), 256, 0, stream>>>(Fq, Fk, partial, diag);
    loss_kernel<<<64, 256, 0, stream>>>(partial, diag, out);
}

// Round 3
// 292.715 us; speedup vs baseline: 1.1127x; 1.1127x over previous
//
#include <hip/hip_runtime.h>
#include <math.h>

#define HWSZ 65536
#define SDIM 2048
#define NCENT 256
#define NCHUNK 32
#define CHUNKSZ 64
#define INV_TAU 14.285714285714286f
#define EPSN 1e-7f

// ---------------- Kernel A: gather-diff -> MLP -> L2 normalize ----------------
// One wave per (which, b, center): gathers the center row (64 ch) + 8 neighbors
// once, then runs the 8 per-offset MLPs with ILP. 1024 blocks x 4 waves.
__global__ __launch_bounds__(256) void feat_kernel(
    const float* __restrict__ f_q, const float* __restrict__ f_k,
    const float* __restrict__ W0, const float* __restrict__ b0,
    const float* __restrict__ W1, const float* __restrict__ b1,
    const int* __restrict__ c_ids, const int* __restrict__ n_ids,
    float* __restrict__ Fq, float* __restrict__ Fk)
{
    __shared__ float sd[4][8][65];   // +1 pad: layer-2 reads hit 4 banks, not 1
    __shared__ float sh[4][8][65];
    const int w    = threadIdx.x >> 6;
    const int lane = threadIdx.x & 63;
    const int row  = blockIdx.x * 4 + w;       // 0..4095
    const int which = row >> 11;               // 0 = f_q, 1 = f_k
    const int r = row & 2047;
    const int b = r >> 8;
    const int cidx = r & 255;                  // center index 0..255

    const float* feat = which ? f_k : f_q;
    const int cid = c_ids[cidx];               // c_ids is tile(c,8)
    // lane = channel
    const float* base = feat + ((size_t)(b * 64 + lane)) * HWSZ;
    const float cval = base[cid];
    #pragma unroll
    for (int k = 0; k < 8; ++k) {
        const int nid = n_ids[cidx + 256 * k];
        sd[w][k][lane] = cval - base[nid];
    }
    __syncthreads();

    // layer 1: lane = j; 8 independent accumulators, W0 row reused 8x
    float acc[8];
    #pragma unroll
    for (int k = 0; k < 8; ++k) acc[k] = b0[lane];
    for (int c = 0; c < 64; ++c) {
        const float w0 = W0[c * 64 + lane];
        #pragma unroll
        for (int k = 0; k < 8; ++k)
            acc[k] = fmaf(sd[w][k][c], w0, acc[k]);
    }
    #pragma unroll
    for (int k = 0; k < 8; ++k) sh[w][k][lane] = fmaxf(acc[k], 0.0f);
    __syncthreads();

    // layer 2: lane = k0*16 + i; two passes cover k = 0..7
    const int i  = lane & 15;
    const int k0 = lane >> 4;
    float* F = which ? Fk : Fq;
    #pragma unroll
    for (int p = 0; p < 2; ++p) {
        const int k = p * 4 + k0;
        float o = b1[i];
        #pragma unroll 16
        for (int j = 0; j < 64; ++j)
            o = fmaf(sh[w][k][j], W1[j * 16 + i], o);
        float s2 = o * o;
        s2 += __shfl_xor(s2, 1, 16);
        s2 += __shfl_xor(s2, 2, 16);
        s2 += __shfl_xor(s2, 4, 16);
        s2 += __shfl_xor(s2, 8, 16);
        const float val = o / (sqrtf(s2) + EPSN);
        const int s = cidx + 256 * k;
        F[((size_t)(b * SDIM + s)) * 16 + i] = val;
    }
}

// ---------------- Kernel B: Gram row partial logsumexp sums ----------------
// grid = (S/256, NCHUNK, B) = 2048 blocks -> 8 waves/SIMD.
__global__ __launch_bounds__(256) void gram_kernel(
    const float* __restrict__ Fq, const float* __restrict__ Fk,
    float* __restrict__ partial, float* __restrict__ diag)
{
    const int s     = blockIdx.x * 256 + threadIdx.x;
    const int chunk = blockIdx.y;
    const int b     = blockIdx.z;

    const float4* q4 = (const float4*)(Fq + ((size_t)(b * SDIM + s)) * 16);
    const float4 qa = q4[0], qb = q4[1], qc = q4[2], qd = q4[3];
    const float* fk = Fk + (size_t)b * SDIM * 16;

    float sum_e = 0.0f;
    float dsave = 0.0f;
    const int t0 = chunk * CHUNKSZ;
    #pragma unroll 2
    for (int t = t0; t < t0 + CHUNKSZ; ++t) {
        const float4* k4 = (const float4*)(fk + (size_t)t * 16);
        const float4 ka = k4[0], kb = k4[1], kc = k4[2], kd = k4[3];
        float dot = qa.x * ka.x;
        dot = fmaf(qa.y, ka.y, dot); dot = fmaf(qa.z, ka.z, dot); dot = fmaf(qa.w, ka.w, dot);
        dot = fmaf(qb.x, kb.x, dot); dot = fmaf(qb.y, kb.y, dot); dot = fmaf(qb.z, kb.z, dot); dot = fmaf(qb.w, kb.w, dot);
        dot = fmaf(qc.x, kc.x, dot); dot = fmaf(qc.y, kc.y, dot); dot = fmaf(qc.z, kc.z, dot); dot = fmaf(qc.w, kc.w, dot);
        dot = fmaf(qd.x, kd.x, dot); dot = fmaf(qd.y, kd.y, dot); dot = fmaf(qd.z, kd.z, dot); dot = fmaf(qd.w, kd.w, dot);
        sum_e += __expf(fmaf(dot, INV_TAU, -INV_TAU));   // exp(dot/tau - 1/tau)
        if (t == s) dsave = dot;
    }
    // layout [chunk][b][s]: coalesced store, coalesced reads in loss_kernel
    partial[(size_t)chunk * 16384 + b * SDIM + s] = sum_e;
    if (chunk == (s >> 6)) diag[b * SDIM + s] = dsave;
}

// ---------------- Kernel C: finalize loss ----------------
__global__ __launch_bounds__(256) void loss_kernel(
    const float* __restrict__ partial, const float* __restrict__ diag,
    float* __restrict__ out)
{
    const int idx = blockIdx.x * 256 + threadIdx.x;  // 0..16383 = b*S+s
    float tot = 0.0f;
    #pragma unroll
    for (int c = 0; c < NCHUNK; ++c) tot += partial[(size_t)c * 16384 + idx];
    float loss = INV_TAU + logf(tot) - diag[idx] * INV_TAU;

    loss += __shfl_xor(loss, 32, 64);
    loss += __shfl_xor(loss, 16, 64);
    loss += __shfl_xor(loss, 8, 64);
    loss += __shfl_xor(loss, 4, 64);
    loss += __shfl_xor(loss, 2, 64);
    loss += __shfl_xor(loss, 1, 64);

    __shared__ float wsum[4];
    const int lane = threadIdx.x & 63, w = threadIdx.x >> 6;
    if (lane == 0) wsum[w] = loss;
    __syncthreads();
    if (threadIdx.x == 0) {
        float blk = wsum[0] + wsum[1] + wsum[2] + wsum[3];
        atomicAdd(out, blk * (1.0f / 16384.0f));
    }
}

extern "C" void kernel_launch(void* const* d_in, const int* in_sizes, int n_in,
                              void* d_out, int out_size, void* d_ws, size_t ws_size,
                              hipStream_t stream) {
    const float* f_q   = (const float*)d_in[0];
    const float* f_k   = (const float*)d_in[1];
    const float* W0    = (const float*)d_in[2];
    const float* b0    = (const float*)d_in[3];
    const float* W1    = (const float*)d_in[4];
    const float* b1    = (const float*)d_in[5];
    const int*   c_ids = (const int*)d_in[6];
    const int*   n_ids = (const int*)d_in[7];

    float* ws      = (float*)d_ws;
    float* Fq      = ws;                  // B*S*16 = 262144 floats
    float* Fk      = Fq + 262144;         // 262144 floats
    float* partial = Fk + 262144;         // NCHUNK*B*S = 524288 floats
    float* diag    = partial + 524288;    // B*S = 16384 floats
    float* out     = (float*)d_out;

    hipMemsetAsync(d_out, 0, sizeof(float), stream);
    feat_kernel<<<1024, 256, 0, stream>>>(f_q, f_k, W0, b0, W1, b1, c_ids, n_ids, Fq, Fk);
    gram_kernel<<<dim3(SDIM / 256, NCHUNK, 8), 256, 0, stream>>>(Fq, Fk, partial, diag);
    loss_kernel<<<64, 256, 0, stream>>>(partial, diag, out);
}

// Round 4
// 287.808 us; speedup vs baseline: 1.1317x; 1.0170x over previous
//
#include <hip/hip_runtime.h>
#include <math.h>

#define HWSZ 65536
#define SDIM 2048
#define NCHUNK 32
#define CHUNKSZ 64
#define INV_TAU 14.285714285714286f
#define EPSN 1e-7f

// ---------------- Kernel A: gather-diff -> MLP -> L2 normalize ----------------
// One wave per (which, b, center). LDS laid out for b128 access:
//   sd[w][c][12]: k contiguous (stride 48 B, 16B-aligned, conflict-free b128)
//   sh[w][k][68]: j contiguous (stride 272 B, bank-shifted across k)
__global__ __launch_bounds__(256) void feat_kernel(
    const float* __restrict__ f_q, const float* __restrict__ f_k,
    const float* __restrict__ W0, const float* __restrict__ b0,
    const float* __restrict__ W1, const float* __restrict__ b1,
    const int* __restrict__ c_ids, const int* __restrict__ n_ids,
    float* __restrict__ Fq, float* __restrict__ Fk)
{
    __shared__ float sd[4][64][12];
    __shared__ float sh[4][8][68];
    const int w    = threadIdx.x >> 6;
    const int lane = threadIdx.x & 63;
    const int row  = blockIdx.x * 4 + w;       // 0..4095
    const int which = row >> 11;               // 0 = f_q, 1 = f_k
    const int r = row & 2047;
    const int b = r >> 8;
    const int cidx = r & 255;                  // center index

    const float* feat = which ? f_k : f_q;
    const int cid = c_ids[cidx];
    const float* base = feat + ((size_t)(b * 64 + lane)) * HWSZ;  // lane = channel
    const float cval = base[cid];
    float4 d0, d1;
    d0.x = cval - base[n_ids[cidx          ]];
    d0.y = cval - base[n_ids[cidx + 256 * 1]];
    d0.z = cval - base[n_ids[cidx + 256 * 2]];
    d0.w = cval - base[n_ids[cidx + 256 * 3]];
    d1.x = cval - base[n_ids[cidx + 256 * 4]];
    d1.y = cval - base[n_ids[cidx + 256 * 5]];
    d1.z = cval - base[n_ids[cidx + 256 * 6]];
    d1.w = cval - base[n_ids[cidx + 256 * 7]];
    *(float4*)&sd[w][lane][0] = d0;
    *(float4*)&sd[w][lane][4] = d1;
    __syncthreads();

    // layer 1: lane = j; 8 samples per wave, broadcast b128 reads of d
    float acc[8];
    const float bias0 = b0[lane];
    #pragma unroll
    for (int k = 0; k < 8; ++k) acc[k] = bias0;
    #pragma unroll 8
    for (int c = 0; c < 64; ++c) {
        const float w0 = W0[c * 64 + lane];
        const float4 a = *(const float4*)&sd[w][c][0];
        const float4 e = *(const float4*)&sd[w][c][4];
        acc[0] = fmaf(a.x, w0, acc[0]);
        acc[1] = fmaf(a.y, w0, acc[1]);
        acc[2] = fmaf(a.z, w0, acc[2]);
        acc[3] = fmaf(a.w, w0, acc[3]);
        acc[4] = fmaf(e.x, w0, acc[4]);
        acc[5] = fmaf(e.y, w0, acc[5]);
        acc[6] = fmaf(e.z, w0, acc[6]);
        acc[7] = fmaf(e.w, w0, acc[7]);
    }
    #pragma unroll
    for (int k = 0; k < 8; ++k) sh[w][k][lane] = fmaxf(acc[k], 0.0f);
    __syncthreads();

    // layer 2: lane = k0*16 + i; two passes; float4 broadcast reads of h
    const int i  = lane & 15;
    const int k0 = lane >> 4;
    float* F = which ? Fk : Fq;
    #pragma unroll
    for (int p = 0; p < 2; ++p) {
        const int k = p * 4 + k0;
        float o = b1[i];
        #pragma unroll
        for (int j4 = 0; j4 < 16; ++j4) {
            const float4 h4 = *(const float4*)&sh[w][k][j4 * 4];
            o = fmaf(h4.x, W1[(j4 * 4 + 0) * 16 + i], o);
            o = fmaf(h4.y, W1[(j4 * 4 + 1) * 16 + i], o);
            o = fmaf(h4.z, W1[(j4 * 4 + 2) * 16 + i], o);
            o = fmaf(h4.w, W1[(j4 * 4 + 3) * 16 + i], o);
        }
        float s2 = o * o;
        s2 += __shfl_xor(s2, 1, 16);
        s2 += __shfl_xor(s2, 2, 16);
        s2 += __shfl_xor(s2, 4, 16);
        s2 += __shfl_xor(s2, 8, 16);
        const float val = o / (sqrtf(s2) + EPSN);
        const int s = cidx + 256 * k;
        F[((size_t)(b * SDIM + s)) * 16 + i] = val;
    }
}

// ---------------- Kernel B: Gram row partial logsumexp sums ----------------
// grid = (S/256, NCHUNK, B) = 2048 blocks -> 8 waves/SIMD. fk row loads are
// wave-uniform (scalar pipe). Diagonal dot hoisted out of the t-loop.
__global__ __launch_bounds__(256) void gram_kernel(
    const float* __restrict__ Fq, const float* __restrict__ Fk,
    float* __restrict__ partial, float* __restrict__ diag)
{
    const int s     = blockIdx.x * 256 + threadIdx.x;
    const int chunk = blockIdx.y;
    const int b     = blockIdx.z;

    const float4* q4 = (const float4*)(Fq + ((size_t)(b * SDIM + s)) * 16);
    const float4 qa = q4[0], qb = q4[1], qc = q4[2], qd = q4[3];
    const float* fk = Fk + (size_t)b * SDIM * 16;

    float sum0 = 0.0f, sum1 = 0.0f;
    const int t0 = chunk * CHUNKSZ;
    for (int t = t0; t < t0 + CHUNKSZ; t += 2) {
        const float4* ka4 = (const float4*)(fk + (size_t)t * 16);
        const float4* kb4 = (const float4*)(fk + (size_t)(t + 1) * 16);
        const float4 k0a = ka4[0], k0b = ka4[1], k0c = ka4[2], k0d = ka4[3];
        const float4 k1a = kb4[0], k1b = kb4[1], k1c = kb4[2], k1d = kb4[3];
        float da = qa.x * k0a.x, db = qa.x * k1a.x;
        da = fmaf(qa.y, k0a.y, da); db = fmaf(qa.y, k1a.y, db);
        da = fmaf(qa.z, k0a.z, da); db = fmaf(qa.z, k1a.z, db);
        da = fmaf(qa.w, k0a.w, da); db = fmaf(qa.w, k1a.w, db);
        da = fmaf(qb.x, k0b.x, da); db = fmaf(qb.x, k1b.x, db);
        da = fmaf(qb.y, k0b.y, da); db = fmaf(qb.y, k1b.y, db);
        da = fmaf(qb.z, k0b.z, da); db = fmaf(qb.z, k1b.z, db);
        da = fmaf(qb.w, k0b.w, da); db = fmaf(qb.w, k1b.w, db);
        da = fmaf(qc.x, k0c.x, da); db = fmaf(qc.x, k1c.x, db);
        da = fmaf(qc.y, k0c.y, da); db = fmaf(qc.y, k1c.y, db);
        da = fmaf(qc.z, k0c.z, da); db = fmaf(qc.z, k1c.z, db);
        da = fmaf(qc.w, k0c.w, da); db = fmaf(qc.w, k1c.w, db);
        da = fmaf(qd.x, k0d.x, da); db = fmaf(qd.x, k1d.x, db);
        da = fmaf(qd.y, k0d.y, da); db = fmaf(qd.y, k1d.y, db);
        da = fmaf(qd.z, k0d.z, da); db = fmaf(qd.z, k1d.z, db);
        da = fmaf(qd.w, k0d.w, da); db = fmaf(qd.w, k1d.w, db);
        sum0 += __expf(fmaf(da, INV_TAU, -INV_TAU));
        sum1 += __expf(fmaf(db, INV_TAU, -INV_TAU));
    }
    partial[(size_t)chunk * 16384 + b * SDIM + s] = sum0 + sum1;

    if (chunk == (s >> 6)) {
        const float4* kd4 = (const float4*)(fk + (size_t)s * 16);
        const float4 ka = kd4[0], kb = kd4[1], kc = kd4[2], kd = kd4[3];
        float dot = qa.x * ka.x;
        dot = fmaf(qa.y, ka.y, dot); dot = fmaf(qa.z, ka.z, dot); dot = fmaf(qa.w, ka.w, dot);
        dot = fmaf(qb.x, kb.x, dot); dot = fmaf(qb.y, kb.y, dot); dot = fmaf(qb.z, kb.z, dot); dot = fmaf(qb.w, kb.w, dot);
        dot = fmaf(qc.x, kc.x, dot); dot = fmaf(qc.y, kc.y, dot); dot = fmaf(qc.z, kc.z, dot); dot = fmaf(qc.w, kc.w, dot);
        dot = fmaf(qd.x, kd.x, dot); dot = fmaf(qd.y, kd.y, dot); dot = fmaf(qd.z, kd.z, dot); dot = fmaf(qd.w, kd.w, dot);
        diag[b * SDIM + s] = dot;
    }
}

// ---------------- Kernel C: finalize loss ----------------
__global__ __launch_bounds__(256) void loss_kernel(
    const float* __restrict__ partial, const float* __restrict__ diag,
    float* __restrict__ out)
{
    const int idx = blockIdx.x * 256 + threadIdx.x;  // 0..16383 = b*S+s
    float tot = 0.0f;
    #pragma unroll
    for (int c = 0; c < NCHUNK; ++c) tot += partial[(size_t)c * 16384 + idx];
    float loss = INV_TAU + __logf(tot) - diag[idx] * INV_TAU;

    loss += __shfl_xor(loss, 32, 64);
    loss += __shfl_xor(loss, 16, 64);
    loss += __shfl_xor(loss, 8, 64);
    loss += __shfl_xor(loss, 4, 64);
    loss += __shfl_xor(loss, 2, 64);
    loss += __shfl_xor(loss, 1, 64);

    __shared__ float wsum[4];
    const int lane = threadIdx.x & 63, w = threadIdx.x >> 6;
    if (lane == 0) wsum[w] = loss;
    __syncthreads();
    if (threadIdx.x == 0) {
        float blk = wsum[0] + wsum[1] + wsum[2] + wsum[3];
        atomicAdd(out, blk * (1.0f / 16384.0f));
    }
}

extern "C" void kernel_launch(void* const* d_in, const int* in_sizes, int n_in,
                              void* d_out, int out_size, void* d_ws, size_t ws_size,
                              hipStream_t stream) {
    const float* f_q   = (const float*)d_in[0];
    const float* f_k   = (const float*)d_in[1];
    const float* W0    = (const float*)d_in[2];
    const float* b0    = (const float*)d_in[3];
    const float* W1    = (const float*)d_in[4];
    const float* b1    = (const float*)d_in[5];
    const int*   c_ids = (const int*)d_in[6];
    const int*   n_ids = (const int*)d_in[7];

    float* ws      = (float*)d_ws;
    float* Fq      = ws;                  // B*S*16 = 262144 floats
    float* Fk      = Fq + 262144;         // 262144 floats
    float* partial = Fk + 262144;         // NCHUNK*B*S = 524288 floats
    float* diag    = partial + 524288;    // B*S = 16384 floats
    float* out     = (float*)d_out;

    hipMemsetAsync(d_out, 0, sizeof(float), stream);
    feat_kernel<<<1024, 256, 0, stream>>>(f_q, f_k, W0, b0, W1, b1, c_ids, n_ids, Fq, Fk);
    gram_kernel<<<dim3(SDIM / 256, NCHUNK, 8), 256, 0, stream>>>(Fq, Fk, partial, diag);
    loss_kernel<<<64, 256, 0, stream>>>(partial, diag, out);
}